// Round 11
// baseline (357.032 us; speedup 1.0000x reference)
//
#include <hip/hip_runtime.h>

#define NB   4
#define SXX  4096
#define SLL  256
#define DD   1024
#define HH   16
#define DHH  64
#define SKV  4352      // SX + SL
#define MKV  17408     // NB * SKV
#define NSPLIT 8

typedef __attribute__((ext_vector_type(8))) short bfrag;   // 8 bf16 (4 VGPRs), MFMA A/B frag
typedef __attribute__((ext_vector_type(4))) float facc;    // MFMA 16x16 C/D frag

__device__ __forceinline__ unsigned short f2bf(float f){
  unsigned u = __builtin_bit_cast(unsigned, f);
  u = (u + 0x7fffu + ((u >> 16) & 1u)) >> 16;   // RNE
  return (unsigned short)u;
}
__device__ __forceinline__ float bf2f(unsigned short h){
  unsigned u = ((unsigned)h) << 16;
  return __builtin_bit_cast(float, u);
}

#define GLOAD_LDS16(g, lds) __builtin_amdgcn_global_load_lds( \
    (const __attribute__((address_space(1))) unsigned int*)(const void*)(g), \
    (__attribute__((address_space(3))) unsigned int*)(void*)(lds), 16, 0, 0)

// ---- prep, R20: wtrans3 + lnorm merged (R19) + zeroes the attn combine counters
// (two launches upstream of attn -> serial-stream ordering guarantees visibility).
__global__ __launch_bounds__(256) void prep(const float* __restrict__ Wq,
    const float* __restrict__ Wkv, const float* __restrict__ Wo,
    unsigned short* __restrict__ wqt, unsigned short* __restrict__ wkvt,
    unsigned short* __restrict__ wot,
    const float* __restrict__ x, const float* __restrict__ lat,
    const float* __restrict__ gx, const float* __restrict__ bx,
    const float* __restrict__ gl, const float* __restrict__ bl,
    unsigned short* __restrict__ kvin, unsigned int* __restrict__ cnt){
  __shared__ float tsh[32][33];
  int bId = blockIdx.x;
  int t = threadIdx.x;
  if (bId == 4096 && t < 64) cnt[t] = 0;        // attn combine counters (64 bh)
  if (bId < 4096){
    const float* in; unsigned short* out; int N, n0, k0;
    if (bId < 1024){ in = Wq;  out = wqt;  N = DD;   n0 = (bId & 31)*32; k0 = (bId >> 5)*32; }
    else if (bId < 3072){ int b2 = bId - 1024; in = Wkv; out = wkvt; N = 2*DD; n0 = (b2 & 63)*32; k0 = (b2 >> 6)*32; }
    else { int b3 = bId - 3072; in = Wo;  out = wot;  N = DD;   n0 = (b3 & 31)*32; k0 = (b3 >> 5)*32; }
    int tx = t & 31, ty = t >> 5;
    #pragma unroll
    for (int i = 0; i < 4; i++)
      tsh[ty + 8*i][tx] = in[(size_t)(k0 + ty + 8*i) * N + n0 + tx];
    __syncthreads();
    #pragma unroll
    for (int i = 0; i < 4; i++)
      out[(size_t)(n0 + ty + 8*i) * DD + k0 + tx] = f2bf(tsh[tx][ty + 8*i]);
  } else {
    int w = t >> 6, l = t & 63;
    int gr = (bId - 4096) * 4 + w;
    const float* src; const float* g; const float* bt;
    int b, s, off;
    if (gr < NB*SXX){
      b = gr >> 12; s = gr & 4095; off = 0;
      src = x + (size_t)gr * DD; g = gx; bt = bx;
    } else {
      int r = gr - NB*SXX;
      b = r >> 8; s = r & 255; off = SXX;
      src = lat + (size_t)r * DD; g = gl; bt = bl;
    }
    const float4* rp = (const float4*)src;
    float4 v[4];
    float sum = 0.f, sq = 0.f;
    #pragma unroll
    for (int i = 0; i < 4; i++){
      v[i] = rp[l + i*64];
      sum += v[i].x + v[i].y + v[i].z + v[i].w;
      sq  += v[i].x*v[i].x + v[i].y*v[i].y + v[i].z*v[i].z + v[i].w*v[i].w;
    }
    #pragma unroll
    for (int o = 1; o < 64; o <<= 1){ sum += __shfl_xor(sum, o); sq += __shfl_xor(sq, o); }
    float mu = sum * (1.f/DD);
    float rs = rsqrtf(sq*(1.f/DD) - mu*mu + 1e-5f);
    unsigned short* dst = kvin + (size_t)(b*SKV + off + s) * DD;
    #pragma unroll
    for (int i = 0; i < 4; i++){
      float4 gv = ((const float4*)g)[l + i*64];
      float4 bv = ((const float4*)bt)[l + i*64];
      ushort4 o4;
      o4.x = f2bf((v[i].x - mu)*rs*gv.x + bv.x);
      o4.y = f2bf((v[i].y - mu)*rs*gv.y + bv.y);
      o4.z = f2bf((v[i].z - mu)*rs*gv.z + bv.z);
      o4.w = f2bf((v[i].w - mu)*rs*gv.w + bv.w);
      *(ushort4*)(dst + (size_t)(l + i*64)*4) = o4;
    }
  }
}

// ---- small GEMM (o projection), R17: gload_lds16 staging. 64x64 tile, 4 waves.
__global__ __launch_bounds__(256) void gemm64(const unsigned short* __restrict__ A,
    const unsigned short* __restrict__ Bt, int M, int N, int K, float* __restrict__ outF){
  __shared__ alignas(16) unsigned short lA[64*64];
  __shared__ alignas(16) unsigned short lB[64*64];
  int n0 = blockIdx.x * 64, m0 = blockIdx.y * 64;
  int t = threadIdx.x, w = t >> 6, l = t & 63;
  int wr = (w >> 1) * 32, wc = (w & 1) * 32;
  int lr = l & 15, q2 = l >> 4;
  int rA = w*8 + (l >> 3), u = l & 7;
  int swz = (u ^ (rA & 7)) * 8;                  // pre-swizzled global col-group
  const unsigned short* Ag = A  + (size_t)(m0 + rA) * K + swz;
  const unsigned short* Bg = Bt + (size_t)(n0 + rA) * K + swz;
  facc acc00 = (facc)0.f, acc01 = (facc)0.f, acc10 = (facc)0.f, acc11 = (facc)0.f;
  for (int k0 = 0; k0 < K; k0 += 64){
    GLOAD_LDS16(Ag + k0,                 &lA[(w*8)*64]);
    GLOAD_LDS16(Ag + (size_t)32*K + k0,  &lA[(32 + w*8)*64]);
    GLOAD_LDS16(Bg + k0,                 &lB[(w*8)*64]);
    GLOAD_LDS16(Bg + (size_t)32*K + k0,  &lB[(32 + w*8)*64]);
    __syncthreads();
    #pragma unroll
    for (int ks = 0; ks < 2; ks++){
      int cs = ((ks*4 + q2) ^ (lr & 7)) * 8;
      bfrag a0 = *(const bfrag*)&lA[(wr + lr)*64 + cs];
      bfrag a1 = *(const bfrag*)&lA[(wr + 16 + lr)*64 + cs];
      bfrag b0 = *(const bfrag*)&lB[(wc + lr)*64 + cs];
      bfrag b1 = *(const bfrag*)&lB[(wc + 16 + lr)*64 + cs];
      acc00 = __builtin_amdgcn_mfma_f32_16x16x32_bf16(a0, b0, acc00, 0, 0, 0);
      acc01 = __builtin_amdgcn_mfma_f32_16x16x32_bf16(a0, b1, acc01, 0, 0, 0);
      acc10 = __builtin_amdgcn_mfma_f32_16x16x32_bf16(a1, b0, acc10, 0, 0, 0);
      acc11 = __builtin_amdgcn_mfma_f32_16x16x32_bf16(a1, b1, acc11, 0, 0, 0);
    }
    __syncthreads();
  }
  int rl = (l >> 4) * 4, cl = l & 15;
  facc accs[2][2] = {{acc00, acc01},{acc10, acc11}};
  #pragma unroll
  for (int mt = 0; mt < 2; mt++)
  #pragma unroll
  for (int nt = 0; nt < 2; nt++)
  #pragma unroll
  for (int j = 0; j < 4; j++){
    int r = m0 + wr + mt*16 + rl + j;
    int c = n0 + wc + nt*16 + cl;
    outF[(size_t)r * N + c] = accs[mt][nt][j];
  }
}

// ---- kv GEMM, R19 (locked): R12 schedule + gemm_q fused as 32 tail blocks.
__global__ __launch_bounds__(512, 2) void gemm_kv(const unsigned short* __restrict__ A,
    const unsigned short* __restrict__ Bt, const unsigned short* __restrict__ Wqt,
    const float* __restrict__ gamma,
    const float* __restrict__ mask_x, const float* __restrict__ mask_lat,
    unsigned short* __restrict__ outK, unsigned short* __restrict__ outV,
    float* __restrict__ rkm, unsigned short* __restrict__ qn){
  __shared__ alignas(16) unsigned short lds[3 * 24576];  // 147456 B: 3 slots (A 16384 + B 8192 shorts)
  int bid = blockIdx.x;
  int m0, n0;
  const unsigned short* Bbase;
  bool isQ = bid >= 1088;
  if (!isQ){
    int wg = (bid & 7) * 136 + (bid >> 3);               // 1088 = 8 * 136: bijective XCD swizzle
    m0 = (wg >> 4) * 256; n0 = (wg & 15) * 128;
    Bbase = Bt;
  } else {
    int i = bid - 1088;                                  // 32 q-blocks: 4 batches x 8 n-tiles
    m0 = (i >> 3) * SKV + SXX;                           // latent rows of batch i>>3
    n0 = (i & 7) * 128;
    Bbase = Wqt;
  }
  int t = threadIdx.x, w = t >> 6, l = t & 63;
  int wm = w >> 1, wn = w & 1;                           // 4M x 2N waves, 64x64 out each
  int lr = l & 15, q2 = l >> 4;
  int r8 = l >> 3, u = l & 7;
  int swz = (u ^ (r8 & 7)) * 8;                          // pre-swizzled global source (rule #21)
  const unsigned short* Ag = A     + (size_t)(m0 + w*8 + r8) * 1024 + swz;
  const unsigned short* Bg = Bbase + (size_t)(n0 + w*8 + r8) * 1024 + swz;

  facc acc[4][4];
  #pragma unroll
  for (int mt = 0; mt < 4; mt++)
  #pragma unroll
  for (int nt = 0; nt < 4; nt++) acc[mt][nt] = (facc)0.f;

#define SBAR __builtin_amdgcn_sched_barrier(0)
#define KV_BARRIER do { SBAR; __builtin_amdgcn_s_barrier(); SBAR; } while(0)
#define KV_STA(j, i) GLOAD_LDS16(Ag + (size_t)(i)*65536 + (j)*64, \
    &lds[((j) % 3)*24576 + (i)*4096 + w*512])
#define KV_STB(j, i) GLOAD_LDS16(Bg + (size_t)(i)*65536 + (j)*64, \
    &lds[((j) % 3)*24576 + 16384 + (i)*4096 + w*512])
#define KV_LDF(va, vb, j, ks) { \
    const unsigned short* pA = &lds[((j) % 3)*24576 + (wm*64 + lr)*64 + (((ks)*4 + q2) ^ (lr & 7))*8]; \
    const unsigned short* pB = &lds[((j) % 3)*24576 + 16384 + (wn*64 + lr)*64 + (((ks)*4 + q2) ^ (lr & 7))*8]; \
    va[0] = *(const bfrag*)(pA);        va[1] = *(const bfrag*)(pA + 1024); \
    va[2] = *(const bfrag*)(pA + 2048); va[3] = *(const bfrag*)(pA + 3072); \
    vb[0] = *(const bfrag*)(pB);        vb[1] = *(const bfrag*)(pB + 1024); \
    vb[2] = *(const bfrag*)(pB + 2048); vb[3] = *(const bfrag*)(pB + 3072); }
#define KV_MFMA(va, vb) do { \
    __builtin_amdgcn_s_setprio(1); \
    _Pragma("unroll") \
    for (int mt = 0; mt < 4; mt++){ \
      _Pragma("unroll") \
      for (int nt = 0; nt < 4; nt++) \
        acc[mt][nt] = __builtin_amdgcn_mfma_f32_16x16x32_bf16(va[mt], vb[nt], acc[mt][nt], 0, 0, 0); } \
    __builtin_amdgcn_s_setprio(0); } while(0)

  // prologue: stage tiles 0,1 (6 loads each); wait tile 0, keep tile 1 in flight
  KV_STA(0,0); KV_STA(0,1); KV_STA(0,2); KV_STA(0,3); KV_STB(0,0); KV_STB(0,1);
  KV_STA(1,0); KV_STA(1,1); KV_STA(1,2); KV_STA(1,3); KV_STB(1,0); KV_STB(1,1);
  __asm__ volatile("s_waitcnt vmcnt(6)" ::: "memory");
  KV_BARRIER;

  bfrag av[4], bv[4];
  #pragma unroll
  for (int j = 0; j < 16; j++){
    KV_LDF(av, bv, j, 0);
    if (j < 14){ KV_STA(j+2, 0); KV_STA(j+2, 1); KV_STB(j+2, 0); }
    KV_MFMA(av, bv);
    KV_LDF(av, bv, j, 1);
    if (j < 14){ KV_STA(j+2, 2); KV_STA(j+2, 3); KV_STB(j+2, 1); }
    KV_MFMA(av, bv);
    if (j < 14)       { __asm__ volatile("s_waitcnt vmcnt(6)" ::: "memory"); }
    else if (j == 14) { __asm__ volatile("s_waitcnt vmcnt(0)" ::: "memory"); }
    KV_BARRIER;
  }
#undef KV_STA
#undef KV_STB
#undef KV_LDF
#undef KV_MFMA

  if (isQ){
    // q epilogue: f32 staging (256x132 pitch), per-64-col rms, gamma^2*rv/8 (gemm_q math)
    int qb = (bid - 1088) >> 3;
    float* ldsF = (float*)lds;
    #pragma unroll
    for (int mt = 0; mt < 4; mt++)
    #pragma unroll
    for (int nt = 0; nt < 4; nt++)
    #pragma unroll
    for (int j = 0; j < 4; j++)
      ldsF[(wm*64 + mt*16 + q2*4 + j)*132 + wn*64 + nt*16 + lr] = acc[mt][nt][j];
    __syncthreads();
    int s = t >> 1, hf = t & 1;
    const float* src = &ldsF[s*132 + hf*64];
    float ss = 0.f;
    #pragma unroll
    for (int d = 0; d < 64; d++){ float a = src[d]; ss = fmaf(a, a, ss); }
    float rv = 0.125f / fmaxf(sqrtf(ss) * 0.125f, 1e-8f);
    int h = (n0 >> 6) + hf;
    unsigned short* dst = &qn[((size_t)(qb*HH + h)*SLL + s)*DHH];
    #pragma unroll
    for (int i = 0; i < 8; i++){
      ushort4 p; float g;
      g = gamma[i*8+0]; p.x = f2bf(src[i*8+0]*g*g*rv);
      g = gamma[i*8+1]; p.y = f2bf(src[i*8+1]*g*g*rv);
      g = gamma[i*8+2]; p.z = f2bf(src[i*8+2]*g*g*rv);
      g = gamma[i*8+3]; p.w = f2bf(src[i*8+3]*g*g*rv);
      ushort4 q;
      g = gamma[i*8+4]; q.x = f2bf(src[i*8+4]*g*g*rv);
      g = gamma[i*8+5]; q.y = f2bf(src[i*8+5]*g*g*rv);
      g = gamma[i*8+6]; q.z = f2bf(src[i*8+6]*g*g*rv);
      g = gamma[i*8+7]; q.w = f2bf(src[i*8+7]*g*g*rv);
      *(ushort4*)&dst[i*8]     = p;
      *(ushort4*)&dst[i*8 + 4] = q;
    }
    return;
  }

  // kv epilogue: tiles never span batches (SKV = 17*256)
  int b = m0 / SKV, s0 = m0 - b*SKV;
  if (n0 < DD){
    #pragma unroll
    for (int mt = 0; mt < 4; mt++)
    #pragma unroll
    for (int nt = 0; nt < 4; nt++)
    #pragma unroll
    for (int j = 0; j < 4; j++)
      lds[(wm*64 + mt*16 + q2*4 + j)*136 + wn*64 + nt*16 + lr] = f2bf(acc[mt][nt][j]);
    __syncthreads();
    int s = t >> 1, hf = t & 1;
    int srow = s0 + s;
    float cm = (srow < SXX) ? mask_x[b*SXX + srow] : mask_lat[b*SLL + srow - SXX];
    const unsigned short* src = &lds[s*136 + hf*64];
    uint4 wv[8];
    #pragma unroll
    for (int i = 0; i < 8; i++) wv[i] = *(const uint4*)&src[i*8];
    float ss0 = 0.f, ss1 = 0.f;
    #pragma unroll
    for (int i = 0; i < 8; i++){
      const unsigned short* pp = (const unsigned short*)&wv[i];
      #pragma unroll
      for (int e = 0; e < 4; e++){
        float a = bf2f(pp[e]);     ss0 = fmaf(a, a, ss0);
        float c = bf2f(pp[e + 4]); ss1 = fmaf(c, c, ss1);
      }
    }
    float rv = 1.f / fmaxf(sqrtf(ss0 + ss1) * 0.125f, 1e-8f);
    int h = (n0 >> 6) + hf;
    unsigned short* dst = &outK[((size_t)(b*HH + h)*SKV + srow)*DHH];
    #pragma unroll
    for (int i = 0; i < 8; i++)
      *(uint4*)&dst[i*8] = wv[i];
    rkm[((size_t)(b*HH + h))*SKV + srow] = (cm != 0.f) ? rv : -1.f;
  } else {
    #pragma unroll
    for (int mt = 0; mt < 4; mt++)
    #pragma unroll
    for (int nt = 0; nt < 4; nt++){
      ushort4 p;
      p.x = f2bf(acc[mt][nt][0]); p.y = f2bf(acc[mt][nt][1]);
      p.z = f2bf(acc[mt][nt][2]); p.w = f2bf(acc[mt][nt][3]);
      *(ushort4*)&lds[(wn*64 + nt*16 + lr)*264 + wm*64 + mt*16 + q2*4] = p;
    }
    __syncthreads();
    int c = t >> 2, sq = t & 3;
    int hh = ((n0 - DD) >> 6) + (c >> 6), d = c & 63;
    const unsigned short* src = &lds[c*264 + sq*64];
    unsigned short* dst = &outV[((size_t)(b*HH + hh)*DHH + d)*SKV + s0 + sq*64];
    #pragma unroll
    for (int i = 0; i < 8; i++)
      *(uint4*)&dst[i*8] = *(const uint4*)&src[i*8];
  }
}

// ---- flash attention, R20: R18 LDS-staged K/V + INLINE COMBINE. Each (bh,split)
// block stores partials, release-fences, atomicAdd's cnt[bh] (device-scope, XCD-
// coherent); the 8th arriver acquire-fences and combines its bh into ybuf. No spin,
// no ordering assumption — losers exit. Saves the attn_combine launch (+gap).
__global__ __launch_bounds__(256) void attn(const unsigned short* __restrict__ qn,
    const unsigned short* __restrict__ kbuf, const unsigned short* __restrict__ vT,
    const float* __restrict__ rkm, const float* __restrict__ mask_lat,
    float* __restrict__ Opart, float* __restrict__ lpart,
    unsigned int* __restrict__ cnt, unsigned short* __restrict__ ybuf){
  int bh = blockIdx.y, split = blockIdx.z;
  int b = bh >> 4;
  __shared__ alignas(16) unsigned short lK[2][4096];   // [buf][64 key-rows x 64 d] swizzled
  __shared__ alignas(16) unsigned short lV[2][4096];   // [buf][64 d-rows x 64 key] swizzled
  __shared__ unsigned short lP[4][4][16][68];          // per-wave, per-tt P staging
  __shared__ unsigned int isLast;
  int t = threadIdx.x, w = t >> 6, l = t & 63;
  int lr = l & 15, q2 = l >> 4, kq = q2 * 8;
  int r8 = l >> 3, u = l & 7;
  int swz8 = (u ^ (r8 & 7)) * 8;                       // staging source pre-swizzle
  int cs0 = (q2 ^ (lr & 7)) * 8;                       // frag-read swizzled chunks
  int cs1 = ((4 + q2) ^ (lr & 7)) * 8;
  const unsigned short* Kg = kbuf + ((size_t)bh*SKV + w*8 + r8)*DHH + swz8;
  const unsigned short* Vg = vT + (size_t)bh*DHH*SKV + (size_t)(w*8 + r8)*SKV + swz8;

  bfrag aq0[4], aq1[4];
  float rm[4][4];
  #pragma unroll
  for (int tt = 0; tt < 4; tt++){
    const unsigned short* qbase = qn + ((size_t)bh * SLL + tt*64 + w*16 + lr) * DHH;
    aq0[tt] = *(const bfrag*)&qbase[kq];
    aq1[tt] = *(const bfrag*)&qbase[32 + kq];
    #pragma unroll
    for (int j = 0; j < 4; j++) rm[tt][j] = mask_lat[b*SLL + tt*64 + w*16 + q2*4 + j];
  }
  facc O[4][4];
  #pragma unroll
  for (int tt = 0; tt < 4; tt++)
  #pragma unroll
  for (int nt = 0; nt < 4; nt++) O[tt][nt] = (facc)0.f;
  float lsum[4][4];
  #pragma unroll
  for (int tt = 0; tt < 4; tt++)
  #pragma unroll
  for (int j = 0; j < 4; j++) lsum[tt][j] = 0.f;

  int t0 = (split * 68) / NSPLIT, t1 = ((split + 1) * 68) / NSPLIT;
  {
    int key0 = t0 * 64;
    GLOAD_LDS16(Kg + (size_t)key0*DHH,          &lK[0][(w*8)*64]);
    GLOAD_LDS16(Kg + (size_t)(key0+32)*DHH,     &lK[0][(w*8 + 32)*64]);
    GLOAD_LDS16(Vg + key0,                      &lV[0][(w*8)*64]);
    GLOAD_LDS16(Vg + (size_t)32*SKV + key0,     &lV[0][(w*8 + 32)*64]);
  }
  __asm__ volatile("s_waitcnt vmcnt(0)" ::: "memory");
  __builtin_amdgcn_s_barrier();

  int p = 0;
  for (int kt = t0; kt < t1; kt++){
    int key0 = kt * 64;
    bfrag bk0[4], bk1[4], bv0[4], bv1[4]; float rk[4];
    #pragma unroll
    for (int nt = 0; nt < 4; nt++){
      const unsigned short* kr = &lK[p][(nt*16 + lr)*64];
      const unsigned short* vr = &lV[p][(nt*16 + lr)*64];
      bk0[nt] = *(const bfrag*)&kr[cs0];
      bk1[nt] = *(const bfrag*)&kr[cs1];
      bv0[nt] = *(const bfrag*)&vr[cs0];
      bv1[nt] = *(const bfrag*)&vr[cs1];
      rk[nt]  = rkm[(size_t)bh*SKV + key0 + nt*16 + lr];   // <0 => masked key
    }
    if (kt + 1 < t1){
      int kn = key0 + 64;
      GLOAD_LDS16(Kg + (size_t)kn*DHH,        &lK[p^1][(w*8)*64]);
      GLOAD_LDS16(Kg + (size_t)(kn+32)*DHH,   &lK[p^1][(w*8 + 32)*64]);
      GLOAD_LDS16(Vg + kn,                    &lV[p^1][(w*8)*64]);
      GLOAD_LDS16(Vg + (size_t)32*SKV + kn,   &lV[p^1][(w*8 + 32)*64]);
    }
    #pragma unroll
    for (int tt = 0; tt < 4; tt++){
      facc S[4];
      #pragma unroll
      for (int nt = 0; nt < 4; nt++){
        S[nt] = (facc)0.f;
        S[nt] = __builtin_amdgcn_mfma_f32_16x16x32_bf16(aq0[tt], bk0[nt], S[nt], 0, 0, 0);
        S[nt] = __builtin_amdgcn_mfma_f32_16x16x32_bf16(aq1[tt], bk1[nt], S[nt], 0, 0, 0);
      }
      #pragma unroll
      for (int j = 0; j < 4; j++){
        float rs_ = 0.f;
        #pragma unroll
        for (int nt = 0; nt < 4; nt++){
          float x = S[nt][j] * rk[nt];
          float sv = (rk[nt] >= 0.f && rm[tt][j] != 0.f) ? x : -3.0e38f;
          float pz = __expf(sv - 8.0f);
          rs_ += pz;
          lP[w][tt][q2*4 + j][nt*16 + lr] = f2bf(pz);
        }
        lsum[tt][j] += rs_;   // per-lane partial (16-lane reduce deferred)
      }
    }
    __asm__ volatile("s_waitcnt lgkmcnt(0)" ::: "memory");   // wave-private LDS round trip
    #pragma unroll
    for (int tt = 0; tt < 4; tt++){
      bfrag ap0 = *(const bfrag*)&lP[w][tt][lr][kq];
      bfrag ap1 = *(const bfrag*)&lP[w][tt][lr][32 + kq];
      #pragma unroll
      for (int nt = 0; nt < 4; nt++){
        O[tt][nt] = __builtin_amdgcn_mfma_f32_16x16x32_bf16(ap0, bv0[nt], O[tt][nt], 0, 0, 0);
        O[tt][nt] = __builtin_amdgcn_mfma_f32_16x16x32_bf16(ap1, bv1[nt], O[tt][nt], 0, 0, 0);
      }
    }
    __asm__ volatile("s_waitcnt vmcnt(0)" ::: "memory");
    __builtin_amdgcn_s_barrier();
    p ^= 1;
  }
  #pragma unroll
  for (int tt = 0; tt < 4; tt++)
  #pragma unroll
  for (int j = 0; j < 4; j++){
    float L = lsum[tt][j];
    L += __shfl_xor(L, 1); L += __shfl_xor(L, 2);
    L += __shfl_xor(L, 4); L += __shfl_xor(L, 8);
    int srow = tt*64 + w*16 + q2*4 + j;
    size_t obase = (((size_t)split*64 + bh)*SLL + srow)*DHH;
    #pragma unroll
    for (int nt = 0; nt < 4; nt++)
      Opart[obase + nt*16 + lr] = O[tt][nt][j];
    if (lr == 0)
      lpart[((size_t)split*64 + bh)*SLL + srow] = L;
  }
  // ---- inline combine (last arriver per bh)
  __threadfence();                      // release this block's partial stores
  __syncthreads();                      // all threads fenced
  if (t == 0) isLast = (atomicAdd(&cnt[bh], 1u) == NSPLIT - 1) ? 1u : 0u;
  __syncthreads();
  if (isLast){
    __threadfence();                    // acquire: see all splits' stores
    int h = bh & 15;
    // wave w handles srows w, w+4, ...; lane l = d
    for (int sr = w; sr < SLL; sr += 4){
      float L = 0.f, acc = 0.f;
      #pragma unroll
      for (int s = 0; s < NSPLIT; s++){
        L   += lpart[((size_t)s*64 + bh)*SLL + sr];
        acc += Opart[(((size_t)s*64 + bh)*SLL + sr)*DHH + l];
      }
      ybuf[((size_t)b*SLL + sr)*DD + h*DHH + l] = f2bf(acc / L);
    }
  }
}

extern "C" void kernel_launch(void* const* d_in, const int* in_sizes, int n_in,
                              void* d_out, int out_size, void* d_ws, size_t ws_size,
                              hipStream_t stream) {
  const float* x        = (const float*)d_in[0];
  const float* latents  = (const float*)d_in[1];
  const float* mask_x   = (const float*)d_in[2];
  const float* mask_lat = (const float*)d_in[3];
  const float* ln_x_g   = (const float*)d_in[4];
  const float* ln_x_b   = (const float*)d_in[5];
  const float* ln_l_g   = (const float*)d_in[6];
  const float* ln_l_b   = (const float*)d_in[7];
  const float* Wq       = (const float*)d_in[8];
  const float* Wkv      = (const float*)d_in[9];
  const float* qk_gamma = (const float*)d_in[10];
  const float* Wo       = (const float*)d_in[11];
  float* out = (float*)d_out;

  // ws layout (~127 MB). Opart/lpart ALIAS kvin/old-lnlat slot (dead once attn runs);
  // cnt lives in the old-lnlat gap after lpart.
  char* wsb = (char*)d_ws;
  unsigned short* kvin  = (unsigned short*)(wsb + 0);          // [MKV][D] bf16       35651584
  unsigned short* wqt   = (unsigned short*)(wsb + 37748736);   // [D][D] bf16          2097152
  unsigned short* wkvt  = (unsigned short*)(wsb + 39845888);   // [2D][D] bf16         4194304
  unsigned short* wot   = (unsigned short*)(wsb + 44040192);   // [D][D] bf16          2097152
  unsigned short* qnb   = (unsigned short*)(wsb + 50331648);   // [B][H][SL][DH]       2097152
  unsigned short* kbuf  = (unsigned short*)(wsb + 52428800);   // [B][H][SKV][DH]     35651584
  unsigned short* vT    = (unsigned short*)(wsb + 88080384);   // [B][H][DH][SKV]     35651584
  float*          rkm   = (float*)(wsb + 123731968);           // [B*H*SKV] f32        1114112
  unsigned short* ybuf  = (unsigned short*)(wsb + 124846080);  // [B*SL][D] bf16       2097152
  float*          Opart = (float*)(wsb + 0);                   // [8][64][256][64] f32 33554432 (alias kvin)
  float*          lpart = (float*)(wsb + 35651584);            // [8][64][256] f32      524288
  unsigned int*   cnt   = (unsigned int*)(wsb + 36175872);     // [64] combine counters    256

  prep<<<8448, 256, 0, stream>>>(Wq, Wkv, Wo, wqt, wkvt, wot,
                                 x, latents, ln_x_g, ln_x_b, ln_l_g, ln_l_b, kvin, cnt);

  gemm_kv<<<dim3(1120), 512, 0, stream>>>(kvin, wkvt, wqt, qk_gamma,
                                          mask_x, mask_lat, kbuf, vT, rkm, qnb);

  attn<<<dim3(1, NB*HH, NSPLIT), 256, 0, stream>>>(qnb, kbuf, vT, rkm, mask_lat,
                                                   Opart, lpart, cnt, ybuf);

  gemm64<<<dim3(DD/64, (NB*SLL)/64), 256, 0, stream>>>(ybuf, wot, NB*SLL, DD, DD, out);
}

// Round 12
// 307.691 us; speedup vs baseline: 1.1604x; 1.1604x over previous
//
#include <hip/hip_runtime.h>

#define NB   4
#define SXX  4096
#define SLL  256
#define DD   1024
#define HH   16
#define DHH  64
#define SKV  4352      // SX + SL
#define MKV  17408     // NB * SKV
#define NSPLIT 8

typedef __attribute__((ext_vector_type(8))) short bfrag;   // 8 bf16 (4 VGPRs), MFMA A/B frag
typedef __attribute__((ext_vector_type(4))) float facc;    // MFMA 16x16 C/D frag

__device__ __forceinline__ unsigned short f2bf(float f){
  unsigned u = __builtin_bit_cast(unsigned, f);
  u = (u + 0x7fffu + ((u >> 16) & 1u)) >> 16;   // RNE
  return (unsigned short)u;
}
__device__ __forceinline__ float bf2f(unsigned short h){
  unsigned u = ((unsigned)h) << 16;
  return __builtin_bit_cast(float, u);
}

#define GLOAD_LDS16(g, lds) __builtin_amdgcn_global_load_lds( \
    (const __attribute__((address_space(1))) unsigned int*)(const void*)(g), \
    (__attribute__((address_space(3))) unsigned int*)(void*)(lds), 16, 0, 0)

// ---- prep, R19: wtrans3 + lnorm merged into one launch. Blocks 0..4095 transpose
// weights; blocks 4096+ are wave-per-row layernorm (shuffle-only reduce).
// R20 ERRATA (reverted): inline attn-combine via threadfence+atomic caused an L2
// writeback/invalidate storm (512 device-scope fences on non-coherent per-XCD L2s)
// -> attn 136us, all pipes idle. Separate combine kernel gets ordering free from
// the launch boundary. Producer-consumer fusion across XCDs: only with tiny counts.
__global__ __launch_bounds__(256) void prep(const float* __restrict__ Wq,
    const float* __restrict__ Wkv, const float* __restrict__ Wo,
    unsigned short* __restrict__ wqt, unsigned short* __restrict__ wkvt,
    unsigned short* __restrict__ wot,
    const float* __restrict__ x, const float* __restrict__ lat,
    const float* __restrict__ gx, const float* __restrict__ bx,
    const float* __restrict__ gl, const float* __restrict__ bl,
    unsigned short* __restrict__ kvin){
  __shared__ float tsh[32][33];
  int bId = blockIdx.x;
  int t = threadIdx.x;
  if (bId < 4096){
    const float* in; unsigned short* out; int N, n0, k0;
    if (bId < 1024){ in = Wq;  out = wqt;  N = DD;   n0 = (bId & 31)*32; k0 = (bId >> 5)*32; }
    else if (bId < 3072){ int b2 = bId - 1024; in = Wkv; out = wkvt; N = 2*DD; n0 = (b2 & 63)*32; k0 = (b2 >> 6)*32; }
    else { int b3 = bId - 3072; in = Wo;  out = wot;  N = DD;   n0 = (b3 & 31)*32; k0 = (b3 >> 5)*32; }
    int tx = t & 31, ty = t >> 5;
    #pragma unroll
    for (int i = 0; i < 4; i++)
      tsh[ty + 8*i][tx] = in[(size_t)(k0 + ty + 8*i) * N + n0 + tx];
    __syncthreads();
    #pragma unroll
    for (int i = 0; i < 4; i++)
      out[(size_t)(n0 + ty + 8*i) * DD + k0 + tx] = f2bf(tsh[tx][ty + 8*i]);
  } else {
    int w = t >> 6, l = t & 63;
    int gr = (bId - 4096) * 4 + w;
    const float* src; const float* g; const float* bt;
    int b, s, off;
    if (gr < NB*SXX){
      b = gr >> 12; s = gr & 4095; off = 0;
      src = x + (size_t)gr * DD; g = gx; bt = bx;
    } else {
      int r = gr - NB*SXX;
      b = r >> 8; s = r & 255; off = SXX;
      src = lat + (size_t)r * DD; g = gl; bt = bl;
    }
    const float4* rp = (const float4*)src;
    float4 v[4];
    float sum = 0.f, sq = 0.f;
    #pragma unroll
    for (int i = 0; i < 4; i++){
      v[i] = rp[l + i*64];
      sum += v[i].x + v[i].y + v[i].z + v[i].w;
      sq  += v[i].x*v[i].x + v[i].y*v[i].y + v[i].z*v[i].z + v[i].w*v[i].w;
    }
    #pragma unroll
    for (int o = 1; o < 64; o <<= 1){ sum += __shfl_xor(sum, o); sq += __shfl_xor(sq, o); }
    float mu = sum * (1.f/DD);
    float rs = rsqrtf(sq*(1.f/DD) - mu*mu + 1e-5f);
    unsigned short* dst = kvin + (size_t)(b*SKV + off + s) * DD;
    #pragma unroll
    for (int i = 0; i < 4; i++){
      float4 gv = ((const float4*)g)[l + i*64];
      float4 bv = ((const float4*)bt)[l + i*64];
      ushort4 o4;
      o4.x = f2bf((v[i].x - mu)*rs*gv.x + bv.x);
      o4.y = f2bf((v[i].y - mu)*rs*gv.y + bv.y);
      o4.z = f2bf((v[i].z - mu)*rs*gv.z + bv.z);
      o4.w = f2bf((v[i].w - mu)*rs*gv.w + bv.w);
      *(ushort4*)(dst + (size_t)(l + i*64)*4) = o4;
    }
  }
}

// ---- small GEMM (o projection), R17: gload_lds16 staging. 64x64 tile, 4 waves.
__global__ __launch_bounds__(256) void gemm64(const unsigned short* __restrict__ A,
    const unsigned short* __restrict__ Bt, int M, int N, int K, float* __restrict__ outF){
  __shared__ alignas(16) unsigned short lA[64*64];
  __shared__ alignas(16) unsigned short lB[64*64];
  int n0 = blockIdx.x * 64, m0 = blockIdx.y * 64;
  int t = threadIdx.x, w = t >> 6, l = t & 63;
  int wr = (w >> 1) * 32, wc = (w & 1) * 32;
  int lr = l & 15, q2 = l >> 4;
  int rA = w*8 + (l >> 3), u = l & 7;
  int swz = (u ^ (rA & 7)) * 8;                  // pre-swizzled global col-group
  const unsigned short* Ag = A  + (size_t)(m0 + rA) * K + swz;
  const unsigned short* Bg = Bt + (size_t)(n0 + rA) * K + swz;
  facc acc00 = (facc)0.f, acc01 = (facc)0.f, acc10 = (facc)0.f, acc11 = (facc)0.f;
  for (int k0 = 0; k0 < K; k0 += 64){
    GLOAD_LDS16(Ag + k0,                 &lA[(w*8)*64]);
    GLOAD_LDS16(Ag + (size_t)32*K + k0,  &lA[(32 + w*8)*64]);
    GLOAD_LDS16(Bg + k0,                 &lB[(w*8)*64]);
    GLOAD_LDS16(Bg + (size_t)32*K + k0,  &lB[(32 + w*8)*64]);
    __syncthreads();
    #pragma unroll
    for (int ks = 0; ks < 2; ks++){
      int cs = ((ks*4 + q2) ^ (lr & 7)) * 8;
      bfrag a0 = *(const bfrag*)&lA[(wr + lr)*64 + cs];
      bfrag a1 = *(const bfrag*)&lA[(wr + 16 + lr)*64 + cs];
      bfrag b0 = *(const bfrag*)&lB[(wc + lr)*64 + cs];
      bfrag b1 = *(const bfrag*)&lB[(wc + 16 + lr)*64 + cs];
      acc00 = __builtin_amdgcn_mfma_f32_16x16x32_bf16(a0, b0, acc00, 0, 0, 0);
      acc01 = __builtin_amdgcn_mfma_f32_16x16x32_bf16(a0, b1, acc01, 0, 0, 0);
      acc10 = __builtin_amdgcn_mfma_f32_16x16x32_bf16(a1, b0, acc10, 0, 0, 0);
      acc11 = __builtin_amdgcn_mfma_f32_16x16x32_bf16(a1, b1, acc11, 0, 0, 0);
    }
    __syncthreads();
  }
  int rl = (l >> 4) * 4, cl = l & 15;
  facc accs[2][2] = {{acc00, acc01},{acc10, acc11}};
  #pragma unroll
  for (int mt = 0; mt < 2; mt++)
  #pragma unroll
  for (int nt = 0; nt < 2; nt++)
  #pragma unroll
  for (int j = 0; j < 4; j++){
    int r = m0 + wr + mt*16 + rl + j;
    int c = n0 + wc + nt*16 + cl;
    outF[(size_t)r * N + c] = accs[mt][nt][j];
  }
}

// ---- kv GEMM, R19 (locked): R12 schedule + gemm_q fused as 32 tail blocks.
__global__ __launch_bounds__(512, 2) void gemm_kv(const unsigned short* __restrict__ A,
    const unsigned short* __restrict__ Bt, const unsigned short* __restrict__ Wqt,
    const float* __restrict__ gamma,
    const float* __restrict__ mask_x, const float* __restrict__ mask_lat,
    unsigned short* __restrict__ outK, unsigned short* __restrict__ outV,
    float* __restrict__ rkm, unsigned short* __restrict__ qn){
  __shared__ alignas(16) unsigned short lds[3 * 24576];  // 147456 B: 3 slots (A 16384 + B 8192 shorts)
  int bid = blockIdx.x;
  int m0, n0;
  const unsigned short* Bbase;
  bool isQ = bid >= 1088;
  if (!isQ){
    int wg = (bid & 7) * 136 + (bid >> 3);               // 1088 = 8 * 136: bijective XCD swizzle
    m0 = (wg >> 4) * 256; n0 = (wg & 15) * 128;
    Bbase = Bt;
  } else {
    int i = bid - 1088;                                  // 32 q-blocks: 4 batches x 8 n-tiles
    m0 = (i >> 3) * SKV + SXX;                           // latent rows of batch i>>3
    n0 = (i & 7) * 128;
    Bbase = Wqt;
  }
  int t = threadIdx.x, w = t >> 6, l = t & 63;
  int wm = w >> 1, wn = w & 1;                           // 4M x 2N waves, 64x64 out each
  int lr = l & 15, q2 = l >> 4;
  int r8 = l >> 3, u = l & 7;
  int swz = (u ^ (r8 & 7)) * 8;                          // pre-swizzled global source (rule #21)
  const unsigned short* Ag = A     + (size_t)(m0 + w*8 + r8) * 1024 + swz;
  const unsigned short* Bg = Bbase + (size_t)(n0 + w*8 + r8) * 1024 + swz;

  facc acc[4][4];
  #pragma unroll
  for (int mt = 0; mt < 4; mt++)
  #pragma unroll
  for (int nt = 0; nt < 4; nt++) acc[mt][nt] = (facc)0.f;

#define SBAR __builtin_amdgcn_sched_barrier(0)
#define KV_BARRIER do { SBAR; __builtin_amdgcn_s_barrier(); SBAR; } while(0)
#define KV_STA(j, i) GLOAD_LDS16(Ag + (size_t)(i)*65536 + (j)*64, \
    &lds[((j) % 3)*24576 + (i)*4096 + w*512])
#define KV_STB(j, i) GLOAD_LDS16(Bg + (size_t)(i)*65536 + (j)*64, \
    &lds[((j) % 3)*24576 + 16384 + (i)*4096 + w*512])
#define KV_LDF(va, vb, j, ks) { \
    const unsigned short* pA = &lds[((j) % 3)*24576 + (wm*64 + lr)*64 + (((ks)*4 + q2) ^ (lr & 7))*8]; \
    const unsigned short* pB = &lds[((j) % 3)*24576 + 16384 + (wn*64 + lr)*64 + (((ks)*4 + q2) ^ (lr & 7))*8]; \
    va[0] = *(const bfrag*)(pA);        va[1] = *(const bfrag*)(pA + 1024); \
    va[2] = *(const bfrag*)(pA + 2048); va[3] = *(const bfrag*)(pA + 3072); \
    vb[0] = *(const bfrag*)(pB);        vb[1] = *(const bfrag*)(pB + 1024); \
    vb[2] = *(const bfrag*)(pB + 2048); vb[3] = *(const bfrag*)(pB + 3072); }
#define KV_MFMA(va, vb) do { \
    __builtin_amdgcn_s_setprio(1); \
    _Pragma("unroll") \
    for (int mt = 0; mt < 4; mt++){ \
      _Pragma("unroll") \
      for (int nt = 0; nt < 4; nt++) \
        acc[mt][nt] = __builtin_amdgcn_mfma_f32_16x16x32_bf16(va[mt], vb[nt], acc[mt][nt], 0, 0, 0); } \
    __builtin_amdgcn_s_setprio(0); } while(0)

  // prologue: stage tiles 0,1 (6 loads each); wait tile 0, keep tile 1 in flight
  KV_STA(0,0); KV_STA(0,1); KV_STA(0,2); KV_STA(0,3); KV_STB(0,0); KV_STB(0,1);
  KV_STA(1,0); KV_STA(1,1); KV_STA(1,2); KV_STA(1,3); KV_STB(1,0); KV_STB(1,1);
  __asm__ volatile("s_waitcnt vmcnt(6)" ::: "memory");
  KV_BARRIER;

  bfrag av[4], bv[4];
  #pragma unroll
  for (int j = 0; j < 16; j++){
    KV_LDF(av, bv, j, 0);
    if (j < 14){ KV_STA(j+2, 0); KV_STA(j+2, 1); KV_STB(j+2, 0); }
    KV_MFMA(av, bv);
    KV_LDF(av, bv, j, 1);
    if (j < 14){ KV_STA(j+2, 2); KV_STA(j+2, 3); KV_STB(j+2, 1); }
    KV_MFMA(av, bv);
    if (j < 14)       { __asm__ volatile("s_waitcnt vmcnt(6)" ::: "memory"); }
    else if (j == 14) { __asm__ volatile("s_waitcnt vmcnt(0)" ::: "memory"); }
    KV_BARRIER;
  }
#undef KV_STA
#undef KV_STB
#undef KV_LDF
#undef KV_MFMA

  if (isQ){
    // q epilogue: f32 staging (256x132 pitch), per-64-col rms, gamma^2*rv/8 (gemm_q math)
    int qb = (bid - 1088) >> 3;
    float* ldsF = (float*)lds;
    #pragma unroll
    for (int mt = 0; mt < 4; mt++)
    #pragma unroll
    for (int nt = 0; nt < 4; nt++)
    #pragma unroll
    for (int j = 0; j < 4; j++)
      ldsF[(wm*64 + mt*16 + q2*4 + j)*132 + wn*64 + nt*16 + lr] = acc[mt][nt][j];
    __syncthreads();
    int s = t >> 1, hf = t & 1;
    const float* src = &ldsF[s*132 + hf*64];
    float ss = 0.f;
    #pragma unroll
    for (int d = 0; d < 64; d++){ float a = src[d]; ss = fmaf(a, a, ss); }
    float rv = 0.125f / fmaxf(sqrtf(ss) * 0.125f, 1e-8f);
    int h = (n0 >> 6) + hf;
    unsigned short* dst = &qn[((size_t)(qb*HH + h)*SLL + s)*DHH];
    #pragma unroll
    for (int i = 0; i < 8; i++){
      ushort4 p; float g;
      g = gamma[i*8+0]; p.x = f2bf(src[i*8+0]*g*g*rv);
      g = gamma[i*8+1]; p.y = f2bf(src[i*8+1]*g*g*rv);
      g = gamma[i*8+2]; p.z = f2bf(src[i*8+2]*g*g*rv);
      g = gamma[i*8+3]; p.w = f2bf(src[i*8+3]*g*g*rv);
      ushort4 q;
      g = gamma[i*8+4]; q.x = f2bf(src[i*8+4]*g*g*rv);
      g = gamma[i*8+5]; q.y = f2bf(src[i*8+5]*g*g*rv);
      g = gamma[i*8+6]; q.z = f2bf(src[i*8+6]*g*g*rv);
      g = gamma[i*8+7]; q.w = f2bf(src[i*8+7]*g*g*rv);
      *(ushort4*)&dst[i*8]     = p;
      *(ushort4*)&dst[i*8 + 4] = q;
    }
    return;
  }

  // kv epilogue: tiles never span batches (SKV = 17*256)
  int b = m0 / SKV, s0 = m0 - b*SKV;
  if (n0 < DD){
    #pragma unroll
    for (int mt = 0; mt < 4; mt++)
    #pragma unroll
    for (int nt = 0; nt < 4; nt++)
    #pragma unroll
    for (int j = 0; j < 4; j++)
      lds[(wm*64 + mt*16 + q2*4 + j)*136 + wn*64 + nt*16 + lr] = f2bf(acc[mt][nt][j]);
    __syncthreads();
    int s = t >> 1, hf = t & 1;
    int srow = s0 + s;
    float cm = (srow < SXX) ? mask_x[b*SXX + srow] : mask_lat[b*SLL + srow - SXX];
    const unsigned short* src = &lds[s*136 + hf*64];
    uint4 wv[8];
    #pragma unroll
    for (int i = 0; i < 8; i++) wv[i] = *(const uint4*)&src[i*8];
    float ss0 = 0.f, ss1 = 0.f;
    #pragma unroll
    for (int i = 0; i < 8; i++){
      const unsigned short* pp = (const unsigned short*)&wv[i];
      #pragma unroll
      for (int e = 0; e < 4; e++){
        float a = bf2f(pp[e]);     ss0 = fmaf(a, a, ss0);
        float c = bf2f(pp[e + 4]); ss1 = fmaf(c, c, ss1);
      }
    }
    float rv = 1.f / fmaxf(sqrtf(ss0 + ss1) * 0.125f, 1e-8f);
    int h = (n0 >> 6) + hf;
    unsigned short* dst = &outK[((size_t)(b*HH + h)*SKV + srow)*DHH];
    #pragma unroll
    for (int i = 0; i < 8; i++)
      *(uint4*)&dst[i*8] = wv[i];
    rkm[((size_t)(b*HH + h))*SKV + srow] = (cm != 0.f) ? rv : -1.f;
  } else {
    #pragma unroll
    for (int mt = 0; mt < 4; mt++)
    #pragma unroll
    for (int nt = 0; nt < 4; nt++){
      ushort4 p;
      p.x = f2bf(acc[mt][nt][0]); p.y = f2bf(acc[mt][nt][1]);
      p.z = f2bf(acc[mt][nt][2]); p.w = f2bf(acc[mt][nt][3]);
      *(ushort4*)&lds[(wn*64 + nt*16 + lr)*264 + wm*64 + mt*16 + q2*4] = p;
    }
    __syncthreads();
    int c = t >> 2, sq = t & 3;
    int hh = ((n0 - DD) >> 6) + (c >> 6), d = c & 63;
    const unsigned short* src = &lds[c*264 + sq*64];
    unsigned short* dst = &outV[((size_t)(b*HH + hh)*DHH + d)*SKV + s0 + sq*64];
    #pragma unroll
    for (int i = 0; i < 8; i++)
      *(uint4*)&dst[i*8] = *(const uint4*)&src[i*8];
  }
}

// ---- flash attention, R18 (reverted from R20): K/V tiles staged through LDS,
// ring-2, next tile staged at top of current tile. Separate combine kernel.
__global__ __launch_bounds__(256) void attn(const unsigned short* __restrict__ qn,
    const unsigned short* __restrict__ kbuf, const unsigned short* __restrict__ vT,
    const float* __restrict__ rkm, const float* __restrict__ mask_lat,
    float* __restrict__ Opart, float* __restrict__ lpart){
  int bh = blockIdx.y, split = blockIdx.z;
  int b = bh >> 4;
  __shared__ alignas(16) unsigned short lK[2][4096];   // [buf][64 key-rows x 64 d] swizzled
  __shared__ alignas(16) unsigned short lV[2][4096];   // [buf][64 d-rows x 64 key] swizzled
  __shared__ unsigned short lP[4][4][16][68];          // per-wave, per-tt P staging
  int t = threadIdx.x, w = t >> 6, l = t & 63;
  int lr = l & 15, q2 = l >> 4, kq = q2 * 8;
  int r8 = l >> 3, u = l & 7;
  int swz8 = (u ^ (r8 & 7)) * 8;                       // staging source pre-swizzle
  int cs0 = (q2 ^ (lr & 7)) * 8;                       // frag-read swizzled chunks
  int cs1 = ((4 + q2) ^ (lr & 7)) * 8;
  const unsigned short* Kg = kbuf + ((size_t)bh*SKV + w*8 + r8)*DHH + swz8;
  const unsigned short* Vg = vT + (size_t)bh*DHH*SKV + (size_t)(w*8 + r8)*SKV + swz8;

  bfrag aq0[4], aq1[4];
  float rm[4][4];
  #pragma unroll
  for (int tt = 0; tt < 4; tt++){
    const unsigned short* qbase = qn + ((size_t)bh * SLL + tt*64 + w*16 + lr) * DHH;
    aq0[tt] = *(const bfrag*)&qbase[kq];
    aq1[tt] = *(const bfrag*)&qbase[32 + kq];
    #pragma unroll
    for (int j = 0; j < 4; j++) rm[tt][j] = mask_lat[b*SLL + tt*64 + w*16 + q2*4 + j];
  }
  facc O[4][4];
  #pragma unroll
  for (int tt = 0; tt < 4; tt++)
  #pragma unroll
  for (int nt = 0; nt < 4; nt++) O[tt][nt] = (facc)0.f;
  float lsum[4][4];
  #pragma unroll
  for (int tt = 0; tt < 4; tt++)
  #pragma unroll
  for (int j = 0; j < 4; j++) lsum[tt][j] = 0.f;

  int t0 = (split * 68) / NSPLIT, t1 = ((split + 1) * 68) / NSPLIT;
  {
    int key0 = t0 * 64;
    GLOAD_LDS16(Kg + (size_t)key0*DHH,          &lK[0][(w*8)*64]);
    GLOAD_LDS16(Kg + (size_t)(key0+32)*DHH,     &lK[0][(w*8 + 32)*64]);
    GLOAD_LDS16(Vg + key0,                      &lV[0][(w*8)*64]);
    GLOAD_LDS16(Vg + (size_t)32*SKV + key0,     &lV[0][(w*8 + 32)*64]);
  }
  __asm__ volatile("s_waitcnt vmcnt(0)" ::: "memory");
  __builtin_amdgcn_s_barrier();

  int p = 0;
  for (int kt = t0; kt < t1; kt++){
    int key0 = kt * 64;
    bfrag bk0[4], bk1[4], bv0[4], bv1[4]; float rk[4];
    #pragma unroll
    for (int nt = 0; nt < 4; nt++){
      const unsigned short* kr = &lK[p][(nt*16 + lr)*64];
      const unsigned short* vr = &lV[p][(nt*16 + lr)*64];
      bk0[nt] = *(const bfrag*)&kr[cs0];
      bk1[nt] = *(const bfrag*)&kr[cs1];
      bv0[nt] = *(const bfrag*)&vr[cs0];
      bv1[nt] = *(const bfrag*)&vr[cs1];
      rk[nt]  = rkm[(size_t)bh*SKV + key0 + nt*16 + lr];   // <0 => masked key
    }
    if (kt + 1 < t1){
      int kn = key0 + 64;
      GLOAD_LDS16(Kg + (size_t)kn*DHH,        &lK[p^1][(w*8)*64]);
      GLOAD_LDS16(Kg + (size_t)(kn+32)*DHH,   &lK[p^1][(w*8 + 32)*64]);
      GLOAD_LDS16(Vg + kn,                    &lV[p^1][(w*8)*64]);
      GLOAD_LDS16(Vg + (size_t)32*SKV + kn,   &lV[p^1][(w*8 + 32)*64]);
    }
    #pragma unroll
    for (int tt = 0; tt < 4; tt++){
      facc S[4];
      #pragma unroll
      for (int nt = 0; nt < 4; nt++){
        S[nt] = (facc)0.f;
        S[nt] = __builtin_amdgcn_mfma_f32_16x16x32_bf16(aq0[tt], bk0[nt], S[nt], 0, 0, 0);
        S[nt] = __builtin_amdgcn_mfma_f32_16x16x32_bf16(aq1[tt], bk1[nt], S[nt], 0, 0, 0);
      }
      #pragma unroll
      for (int j = 0; j < 4; j++){
        float rs_ = 0.f;
        #pragma unroll
        for (int nt = 0; nt < 4; nt++){
          float x = S[nt][j] * rk[nt];
          float sv = (rk[nt] >= 0.f && rm[tt][j] != 0.f) ? x : -3.0e38f;
          float pz = __expf(sv - 8.0f);
          rs_ += pz;
          lP[w][tt][q2*4 + j][nt*16 + lr] = f2bf(pz);
        }
        lsum[tt][j] += rs_;   // per-lane partial (16-lane reduce deferred)
      }
    }
    __asm__ volatile("s_waitcnt lgkmcnt(0)" ::: "memory");   // wave-private LDS round trip
    #pragma unroll
    for (int tt = 0; tt < 4; tt++){
      bfrag ap0 = *(const bfrag*)&lP[w][tt][lr][kq];
      bfrag ap1 = *(const bfrag*)&lP[w][tt][lr][32 + kq];
      #pragma unroll
      for (int nt = 0; nt < 4; nt++){
        O[tt][nt] = __builtin_amdgcn_mfma_f32_16x16x32_bf16(ap0, bv0[nt], O[tt][nt], 0, 0, 0);
        O[tt][nt] = __builtin_amdgcn_mfma_f32_16x16x32_bf16(ap1, bv1[nt], O[tt][nt], 0, 0, 0);
      }
    }
    __asm__ volatile("s_waitcnt vmcnt(0)" ::: "memory");
    __builtin_amdgcn_s_barrier();
    p ^= 1;
  }
  #pragma unroll
  for (int tt = 0; tt < 4; tt++)
  #pragma unroll
  for (int j = 0; j < 4; j++){
    float L = lsum[tt][j];
    L += __shfl_xor(L, 1); L += __shfl_xor(L, 2);
    L += __shfl_xor(L, 4); L += __shfl_xor(L, 8);
    int srow = tt*64 + w*16 + q2*4 + j;
    size_t obase = (((size_t)split*64 + bh)*SLL + srow)*DHH;
    #pragma unroll
    for (int nt = 0; nt < 4; nt++)
      Opart[obase + nt*16 + lr] = O[tt][nt][j];
    if (lr == 0)
      lpart[((size_t)split*64 + bh)*SLL + srow] = L;
  }
}

// ---- combine partials across splits (fixed-max: plain sums) -> ybuf bf16 [B][SL][D]
__global__ __launch_bounds__(256) void attn_combine(const float* __restrict__ Opart,
    const float* __restrict__ lpart, unsigned short* __restrict__ ybuf){
  int t = threadIdx.x, w = t >> 6, l = t & 63;
  int idx = blockIdx.x * 4 + w;
  int bh = idx >> 8, srow = idx & 255;
  int b = bh >> 4, h = bh & 15;
  float L = 0.f, acc = 0.f;
  #pragma unroll
  for (int s = 0; s < NSPLIT; s++){
    L   += lpart[((size_t)s*64 + bh)*SLL + srow];
    acc += Opart[(((size_t)s*64 + bh)*SLL + srow)*DHH + l];
  }
  ybuf[((size_t)b*SLL + srow)*DD + h*DHH + l] = f2bf(acc / L);
}

extern "C" void kernel_launch(void* const* d_in, const int* in_sizes, int n_in,
                              void* d_out, int out_size, void* d_ws, size_t ws_size,
                              hipStream_t stream) {
  const float* x        = (const float*)d_in[0];
  const float* latents  = (const float*)d_in[1];
  const float* mask_x   = (const float*)d_in[2];
  const float* mask_lat = (const float*)d_in[3];
  const float* ln_x_g   = (const float*)d_in[4];
  const float* ln_x_b   = (const float*)d_in[5];
  const float* ln_l_g   = (const float*)d_in[6];
  const float* ln_l_b   = (const float*)d_in[7];
  const float* Wq       = (const float*)d_in[8];
  const float* Wkv      = (const float*)d_in[9];
  const float* qk_gamma = (const float*)d_in[10];
  const float* Wo       = (const float*)d_in[11];
  float* out = (float*)d_out;

  // ws layout (~127 MB). Opart/lpart ALIAS kvin/old-lnlat slot (dead once attn runs).
  char* wsb = (char*)d_ws;
  unsigned short* kvin  = (unsigned short*)(wsb + 0);          // [MKV][D] bf16       35651584
  unsigned short* wqt   = (unsigned short*)(wsb + 37748736);   // [D][D] bf16          2097152
  unsigned short* wkvt  = (unsigned short*)(wsb + 39845888);   // [2D][D] bf16         4194304
  unsigned short* wot   = (unsigned short*)(wsb + 44040192);   // [D][D] bf16          2097152
  unsigned short* qnb   = (unsigned short*)(wsb + 50331648);   // [B][H][SL][DH]       2097152
  unsigned short* kbuf  = (unsigned short*)(wsb + 52428800);   // [B][H][SKV][DH]     35651584
  unsigned short* vT    = (unsigned short*)(wsb + 88080384);   // [B][H][DH][SKV]     35651584
  float*          rkm   = (float*)(wsb + 123731968);           // [B*H*SKV] f32        1114112
  unsigned short* ybuf  = (unsigned short*)(wsb + 124846080);  // [B*SL][D] bf16       2097152
  float*          Opart = (float*)(wsb + 0);                   // [8][64][256][64] f32 33554432 (alias kvin)
  float*          lpart = (float*)(wsb + 35651584);            // [8][64][256] f32      524288

  prep<<<8448, 256, 0, stream>>>(Wq, Wkv, Wo, wqt, wkvt, wot,
                                 x, latents, ln_x_g, ln_x_b, ln_l_g, ln_l_b, kvin);

  gemm_kv<<<dim3(1120), 512, 0, stream>>>(kvin, wkvt, wqt, qk_gamma,
                                          mask_x, mask_lat, kbuf, vT, rkm, qnb);

  attn<<<dim3(1, NB*HH, NSPLIT), 256, 0, stream>>>(qnb, kbuf, vT, rkm, mask_lat, Opart, lpart);
  attn_combine<<<(NB*HH*SLL)/4, 256, 0, stream>>>(Opart, lpart, ybuf);

  gemm64<<<dim3(DD/64, (NB*SLL)/64), 256, 0, stream>>>(ybuf, wot, NB*SLL, DD, DD, out);
}